// Round 5
// baseline (912.545 us; speedup 1.0000x reference)
//
#include <hip/hip_runtime.h>

// MultiHeadSelfAttention (faithful-bug version): qkv = x@Wqkv^T; attention over
// FULL 1024-dim "head"; scale 1/sqrt(64); probs@v; scramble reshape; proj + bias.
// B=4, S=2048, E=1024, H=1024, 3H=3072.
//
// gemm10: m97-style simple schedule scaled for LDS-BW intensity:
//  - 512 thr / 8 waves (2M x 4N), BN=256, BM in {256,128}, BK=32
//  - LDS dbuf = 64KB (BM=256 -> 2 blocks/CU) or 48KB (BM=128 -> 3 blocks/CU)
//  - one __syncthreads per K-tile; stage-at-top; co-residency hides latency
//  - LDS-BW ceiling model: BM=256: MFMA 310cy vs LDS 625cy -> ~50% MfmaUtil

typedef float f32x4 __attribute__((ext_vector_type(4)));
typedef short bf16x8 __attribute__((ext_vector_type(8)));
typedef short bf16x4 __attribute__((ext_vector_type(4)));
typedef unsigned short u16;

__device__ inline u16 f2bf(float f) {  // round-to-nearest-even f32 -> bf16 bits
  union { float f; unsigned u; } x; x.f = f;
  unsigned r = x.u + 0x7fffu + ((x.u >> 16) & 1u);
  return (u16)(r >> 16);
}

__device__ inline void gload_lds16(const void* g, void* l) {
  __builtin_amdgcn_global_load_lds(
      (const __attribute__((address_space(1))) void*)g,
      (__attribute__((address_space(3))) void*)l, 16, 0, 0);
}

// ---------------- f32 -> bf16 conversion (memory-bound) ----------------
__global__ __launch_bounds__(256) void cvt_kernel(const float* __restrict__ in,
                                                  u16* __restrict__ out, int n8) {
  int i = blockIdx.x * 256 + threadIdx.x;
  if (i >= n8) return;
  f32x4 a = *(const f32x4*)&in[(long)i * 8];
  f32x4 b = *(const f32x4*)&in[(long)i * 8 + 4];
  bf16x8 o;
#pragma unroll
  for (int j = 0; j < 4; ++j) { o[j] = (short)f2bf(a[j]); o[4 + j] = (short)f2bf(b[j]); }
  *(bf16x8*)&out[(long)i * 8] = o;
}

// ---------------- V transpose: vT[b][h][k] = qkv[b][k][2048+h] ----------------
__global__ __launch_bounds__(256) void transpose_v(const u16* __restrict__ qkvb,
                                                   u16* __restrict__ vT) {
  __shared__ u16 tile[64][72];
  const int t = threadIdx.x;
  const long b = blockIdx.z;
  const int k0 = blockIdx.x * 64, h0 = blockIdx.y * 64;
  const u16* v = qkvb + b * 2048 * 3072 + 2048;
#pragma unroll
  for (int i = 0; i < 2; ++i) {
    int s = i * 256 + t; int r = s >> 3, c = (s & 7) * 8;
    bf16x8 val = *(const bf16x8*)&v[(long)(k0 + r) * 3072 + h0 + c];
    *(bf16x8*)&tile[r][c] = val;
  }
  __syncthreads();
  u16* o = vT + b * 1024 * 2048;
#pragma unroll
  for (int i = 0; i < 2; ++i) {
    int s = i * 256 + t; int r = s >> 3, c = (s & 7) * 8;
    bf16x8 val;
#pragma unroll
    for (int j = 0; j < 8; ++j) val[j] = tile[c + j][r];
    *(bf16x8*)&o[(long)(h0 + r) * 2048 + k0 + c] = val;
  }
}

// ---------------- row softmax: probs = softmax(scores * 0.125), bf16 out ------
__global__ __launch_bounds__(256) void softmax_k(const float* __restrict__ S,
                                                 u16* __restrict__ P,
                                                 long sS, long sP) {
  const int t = threadIdx.x;
  const float* row = S + (long)blockIdx.z * sS + (long)blockIdx.x * 2048;
  u16* prow = P + (long)blockIdx.z * sP + (long)blockIdx.x * 2048;
  f32x4 v0 = *(const f32x4*)&row[t * 8];
  f32x4 v1 = *(const f32x4*)&row[t * 8 + 4];
  float m = v0[0];
#pragma unroll
  for (int j = 1; j < 4; ++j) m = fmaxf(m, v0[j]);
#pragma unroll
  for (int j = 0; j < 4; ++j) m = fmaxf(m, v1[j]);
#pragma unroll
  for (int o = 32; o; o >>= 1) m = fmaxf(m, __shfl_xor(m, o));
  __shared__ float red[8];
  if ((t & 63) == 0) red[t >> 6] = m;
  __syncthreads();
  m = fmaxf(fmaxf(red[0], red[1]), fmaxf(red[2], red[3]));
  const float C = 0.18033688011112042f;  // 0.125 * log2(e)
  float e[8], s = 0.f;
#pragma unroll
  for (int j = 0; j < 4; ++j) { e[j] = exp2f((v0[j] - m) * C); s += e[j]; }
#pragma unroll
  for (int j = 0; j < 4; ++j) { e[4 + j] = exp2f((v1[j] - m) * C); s += e[4 + j]; }
#pragma unroll
  for (int o = 32; o; o >>= 1) s += __shfl_xor(s, o);
  if ((t & 63) == 0) red[4 + (t >> 6)] = s;
  __syncthreads();
  float inv = 1.f / (red[4] + red[5] + red[6] + red[7]);
  bf16x8 ov;
#pragma unroll
  for (int j = 0; j < 8; ++j) ov[j] = (short)f2bf(e[j] * inv);
  *(bf16x8*)&prow[t * 8] = ov;
}

// ======== gemm10: NT GEMM C[m][n] = sum_k A[m][k]*B[n][k], BK=32 ==============
// MODE 0: f32 store | 1: bf16 store | 2: bf16 scramble store (PV) | 3: f32+bias
template <int MODE, int BM, int MINW>
__global__ __launch_bounds__(512, MINW) void gemm10(const u16* __restrict__ A0, int lda, long sAz,
                                                    const u16* __restrict__ B0, int ldb, long sBz,
                                                    void* __restrict__ C0, int ldc, long sCz,
                                                    const float* __restrict__ bias, int K) {
  constexpr int MR = BM / 32;   // A frags per wave (8 or 4)
  constexpr int LA = BM / 128;  // A stage rounds (2 or 1); B is always 2
  extern __shared__ __align__(16) u16 smem[];
  u16* Ab = smem;                  // [2][BM][32]
  u16* Bb = smem + 2 * BM * 32;    // [2][256][32]
  const int t = threadIdx.x, lane = t & 63, wv = t >> 6;
  const int wr = wv >> 2, wc = wv & 3;
  const int fr = lane & 15, hi = lane >> 4;

  // bijective XCD-chunk swizzle over the full grid (all our grids are %8==0)
  const int gx = gridDim.x, gy = gridDim.y;
  long L = ((long)blockIdx.z * gy + blockIdx.y) * gx + blockIdx.x;
  const long NB = (long)gx * gy * gridDim.z;
  if ((NB & 7) == 0) L = (L & 7) * (NB >> 3) + (L >> 3);
  const int bx = (int)(L % gx);
  const int by = (int)((L / gx) % gy);
  const int bz = (int)(L / ((long)gx * gy));

  const long row0 = (long)by * BM, col0 = (long)bx * 256;
  const u16* A = A0 + (long)bz * sAz;
  const u16* B = B0 + (long)bz * sBz;

  f32x4 acc[MR][4];
#pragma unroll
  for (int m = 0; m < MR; ++m)
#pragma unroll
    for (int n = 0; n < 4; ++n) acc[m][n] = (f32x4){0.f, 0.f, 0.f, 0.f};

  auto stage = [&](int buf, int k0) {
#pragma unroll
    for (int i = 0; i < LA; ++i) {
      const int l = i * 512 + t;
      const int r = l >> 2, sl = l & 3;
      gload_lds16(A + (row0 + r) * (long)lda + k0 + sl * 8,
                  Ab + buf * BM * 32 + (i * 512 + wv * 64) * 8);
    }
#pragma unroll
    for (int i = 0; i < 2; ++i) {
      const int l = i * 512 + t;
      const int r = l >> 2, sl = l & 3;
      gload_lds16(B + (col0 + r) * (long)ldb + k0 + sl * 8,
                  Bb + buf * 256 * 32 + (i * 512 + wv * 64) * 8);
    }
  };

  // prologue
  stage(0, 0);
  __syncthreads();

  const int NT = K >> 5;
  for (int kt = 0; kt < NT; ++kt) {
    const int cur = kt & 1;
    if (kt + 1 < NT) stage(cur ^ 1, (kt + 1) << 5);
    bf16x8 afr[MR], bfr[4];
#pragma unroll
    for (int m = 0; m < MR; ++m)
      afr[m] = *(const bf16x8*)(Ab + (cur * BM + wr * (BM / 2) + m * 16 + fr) * 32 + hi * 8);
#pragma unroll
    for (int n = 0; n < 4; ++n)
      bfr[n] = *(const bf16x8*)(Bb + (cur * 256 + wc * 64 + n * 16 + fr) * 32 + hi * 8);
#pragma unroll
    for (int m = 0; m < MR; ++m)
#pragma unroll
      for (int n = 0; n < 4; ++n)
        acc[m][n] = __builtin_amdgcn_mfma_f32_16x16x32_bf16(afr[m], bfr[n], acc[m][n], 0, 0, 0);
    __syncthreads();  // drains vmcnt (next-tile stage) + lgkm; frees cur for overwrite
  }

  // epilogue
#pragma unroll
  for (int m = 0; m < MR; ++m)
#pragma unroll
    for (int n = 0; n < 4; ++n) {
      const long r0 = row0 + wr * (BM / 2) + m * 16 + hi * 4;
      const long c = col0 + wc * 64 + n * 16 + fr;
      if (MODE == 0) {
        float* C = (float*)C0 + (long)bz * sCz;
#pragma unroll
        for (int j = 0; j < 4; ++j) C[(r0 + j) * ldc + c] = acc[m][n][j];
      } else if (MODE == 1) {
        u16* C = (u16*)C0 + (long)bz * sCz;
#pragma unroll
        for (int j = 0; j < 4; ++j) C[(r0 + j) * ldc + c] = f2bf(acc[m][n][j]);
      } else if (MODE == 2) {
        // m-dim = q within batch, n-dim = h; scramble: out2[2h + (q>>10)][q&1023]
        u16* C = (u16*)C0 + (long)bz * sCz;
        const int q0 = (int)r0;
        const long dr = 2 * c + (q0 >> 10);
        bf16x4 pk;
#pragma unroll
        for (int j = 0; j < 4; ++j) pk[j] = (short)f2bf(acc[m][n][j]);
        *(bf16x4*)&C[dr * 1024 + (q0 & 1023)] = pk;
      } else {
        float* C = (float*)C0 + (long)bz * sCz;
        const float bv = bias[c];
#pragma unroll
        for (int j = 0; j < 4; ++j) C[(r0 + j) * ldc + c] = acc[m][n][j] + bv;
      }
    }
}

// ---------------- launch ----------------
extern "C" void kernel_launch(void* const* d_in, const int* in_sizes, int n_in,
                              void* d_out, int out_size, void* d_ws, size_t ws_size,
                              hipStream_t stream) {
  const float* x      = (const float*)d_in[0];  // [4,2048,1024]
  const float* w_qkv  = (const float*)d_in[1];  // [3072,1024]
  const float* w_proj = (const float*)d_in[2];  // [1024,1024]
  const float* b_proj = (const float*)d_in[3];  // [1024]
  float* out = (float*)d_out;                   // [4,2048,1024]
  char* ws = (char*)d_ws;

  // ws layout (bytes)
  u16*   xb     = (u16*)(ws + 0);          // 16 MB
  u16*   wqkvb  = (u16*)(ws + 16777216);   //  6 MB
  u16*   wprojb = (u16*)(ws + 23068672);   //  2 MB
  u16*   qkvb   = (u16*)(ws + 25165824);   // 48 MB  [8192][3072]
  u16*   vT     = (u16*)(ws + 75497472);   // 16 MB  [4][1024][2048]
  u16*   out2   = (u16*)(ws + 92274688);   // 16 MB  [8192][1024] scrambled
  float* scores = (float*)(ws + 109051904);
  const bool full = ws_size >= 209715200ull;
  u16* probs = (u16*)(ws + (full ? 176160768 : 125829120));

  const int L256 = (2 * 256 * 32 + 2 * 256 * 32) * 2;  // 64 KB -> 2 blocks/CU
  const int L128 = (2 * 128 * 32 + 2 * 256 * 32) * 2;  // 48 KB -> 3 blocks/CU
  hipFuncSetAttribute((const void*)gemm10<1, 256, 4>, hipFuncAttributeMaxDynamicSharedMemorySize, L256);
  hipFuncSetAttribute((const void*)gemm10<0, 256, 4>, hipFuncAttributeMaxDynamicSharedMemorySize, L256);
  hipFuncSetAttribute((const void*)gemm10<2, 128, 6>, hipFuncAttributeMaxDynamicSharedMemorySize, L128);
  hipFuncSetAttribute((const void*)gemm10<3, 128, 6>, hipFuncAttributeMaxDynamicSharedMemorySize, L128);

  // 1) f32 -> bf16
  cvt_kernel<<<4096, 256, 0, stream>>>(x, xb, 1048576);
  cvt_kernel<<<1536, 256, 0, stream>>>(w_qkv, wqkvb, 393216);
  cvt_kernel<<<512, 256, 0, stream>>>(w_proj, wprojb, 131072);

  // 2) qkv = x @ w_qkv^T  (M=8192, N=3072, K=1024) -> bf16; 384 blocks, 2-res
  gemm10<1, 256, 4><<<dim3(12, 32, 1), 512, L256, stream>>>(xb, 1024, 0, wqkvb, 1024, 0,
                                                            qkvb, 3072, 0, nullptr, 1024);
  // 3) vT
  transpose_v<<<dim3(32, 16, 4), 256, 0, stream>>>(qkvb, vT);

  const long sQ = 2048L * 3072;
  if (full) {
    // 4) scores = q @ k^T (f32); 256 blocks
    gemm10<0, 256, 4><<<dim3(8, 8, 4), 512, L256, stream>>>(qkvb, 3072, sQ, qkvb + 1024, 3072, sQ,
                                                            scores, 2048, 2048L * 2048, nullptr, 1024);
    softmax_k<<<dim3(2048, 1, 4), 256, 0, stream>>>(scores, probs, 2048L * 2048, 2048L * 2048);
    // 5) out2 = probs @ vT^T (M=2048, N=1024, K=2048), scramble store; 256 blocks
    gemm10<2, 128, 6><<<dim3(4, 16, 4), 512, L128, stream>>>(probs, 2048, 2048L * 2048, vT, 2048, 2048L * 1024,
                                                             out2, 1024, 2048L * 1024, nullptr, 2048);
  } else {
    for (int b = 0; b < 4; ++b) {
      const u16* qb = qkvb + (long)b * sQ;
      gemm10<0, 256, 4><<<dim3(8, 8, 1), 512, L256, stream>>>(qb, 3072, 0, qb + 1024, 3072, 0,
                                                              scores, 2048, 0, nullptr, 1024);
      softmax_k<<<dim3(2048, 1, 1), 256, 0, stream>>>(scores, probs, 0, 0);
      gemm10<2, 128, 6><<<dim3(4, 16, 1), 512, L128, stream>>>(probs, 2048, 0, vT + (long)b * 2048 * 1024, 2048, 0,
                                                               out2 + (long)b * 2048 * 1024, 1024, 0, nullptr, 2048);
    }
  }

  // 6) out = out2 @ w_proj^T + b_proj (M=8192, N=1024, K=1024) -> f32; 256 blocks
  gemm10<3, 128, 6><<<dim3(4, 64, 1), 512, L128, stream>>>(out2, 1024, 0, wprojb, 1024, 0,
                                                           out, 1024, 0, b_proj, 1024);
}

// Round 6
// 321.320 us; speedup vs baseline: 2.8400x; 2.8400x over previous
//
#include <hip/hip_runtime.h>

// MultiHeadSelfAttention (faithful-bug version): qkv = x@Wqkv^T; attention over
// FULL 1024-dim "head"; scale 1/sqrt(64); probs@v; scramble reshape; proj + bias.
// B=4, S=2048, E=1024, H=1024, 3H=3072.
//
// gemm11: m201-faithful deep-pipelined NT GEMM.
//  - 512 thr / 8 waves (2M x 4N), BN=256, BM in {128,256}; wave tile (BM/2)x64
//  - LDS units [2dbuf][2kh][R][32] bf16 (64B rows, conflict-free-by-tiling)
//  - per K-tile(64): 4 phases (BM=256) or 2 phases (BM=128); each phase:
//      ds-reads -> stage 1 unit(other dbuf) -> barrier -> lgkmcnt(0) ->
//      setprio(1) 16 MFMA setprio(0) [-> vmcnt(N) ] -> barrier
//  - vmcnt(N) BEFORE a barrier publishes each wave's stage completion to all
//    waves before dependent ds_reads (cross-wave-sound counted prefetch).

typedef float f32x4 __attribute__((ext_vector_type(4)));
typedef short bf16x8 __attribute__((ext_vector_type(8)));
typedef short bf16x4 __attribute__((ext_vector_type(4)));
typedef unsigned short u16;

__device__ inline u16 f2bf(float f) {  // round-to-nearest-even f32 -> bf16 bits
  union { float f; unsigned u; } x; x.f = f;
  unsigned r = x.u + 0x7fffu + ((x.u >> 16) & 1u);
  return (u16)(r >> 16);
}

__device__ inline void gload_lds16(const void* g, void* l) {
  __builtin_amdgcn_global_load_lds(
      (const __attribute__((address_space(1))) void*)g,
      (__attribute__((address_space(3))) void*)l, 16, 0, 0);
}

// ---------------- f32 -> bf16 conversion (memory-bound) ----------------
__global__ __launch_bounds__(256) void cvt_kernel(const float* __restrict__ in,
                                                  u16* __restrict__ out, int n8) {
  int i = blockIdx.x * 256 + threadIdx.x;
  if (i >= n8) return;
  f32x4 a = *(const f32x4*)&in[(long)i * 8];
  f32x4 b = *(const f32x4*)&in[(long)i * 8 + 4];
  bf16x8 o;
#pragma unroll
  for (int j = 0; j < 4; ++j) { o[j] = (short)f2bf(a[j]); o[4 + j] = (short)f2bf(b[j]); }
  *(bf16x8*)&out[(long)i * 8] = o;
}

// ---------------- V transpose: vT[b][h][k] = qkv[b][k][2048+h] ----------------
__global__ __launch_bounds__(256) void transpose_v(const u16* __restrict__ qkvb,
                                                   u16* __restrict__ vT) {
  __shared__ u16 tile[64][72];
  const int t = threadIdx.x;
  const long b = blockIdx.z;
  const int k0 = blockIdx.x * 64, h0 = blockIdx.y * 64;
  const u16* v = qkvb + b * 2048 * 3072 + 2048;
#pragma unroll
  for (int i = 0; i < 2; ++i) {
    int s = i * 256 + t; int r = s >> 3, c = (s & 7) * 8;
    bf16x8 val = *(const bf16x8*)&v[(long)(k0 + r) * 3072 + h0 + c];
    *(bf16x8*)&tile[r][c] = val;
  }
  __syncthreads();
  u16* o = vT + b * 1024 * 2048;
#pragma unroll
  for (int i = 0; i < 2; ++i) {
    int s = i * 256 + t; int r = s >> 3, c = (s & 7) * 8;
    bf16x8 val;
#pragma unroll
    for (int j = 0; j < 8; ++j) val[j] = tile[c + j][r];
    *(bf16x8*)&o[(long)(h0 + r) * 2048 + k0 + c] = val;
  }
}

// ---------------- row softmax: probs = softmax(scores * 0.125), bf16 out ------
__global__ __launch_bounds__(256) void softmax_k(const float* __restrict__ S,
                                                 u16* __restrict__ P,
                                                 long sS, long sP) {
  const int t = threadIdx.x;
  const float* row = S + (long)blockIdx.z * sS + (long)blockIdx.x * 2048;
  u16* prow = P + (long)blockIdx.z * sP + (long)blockIdx.x * 2048;
  f32x4 v0 = *(const f32x4*)&row[t * 8];
  f32x4 v1 = *(const f32x4*)&row[t * 8 + 4];
  float m = v0[0];
#pragma unroll
  for (int j = 1; j < 4; ++j) m = fmaxf(m, v0[j]);
#pragma unroll
  for (int j = 0; j < 4; ++j) m = fmaxf(m, v1[j]);
#pragma unroll
  for (int o = 32; o; o >>= 1) m = fmaxf(m, __shfl_xor(m, o));
  __shared__ float red[8];
  if ((t & 63) == 0) red[t >> 6] = m;
  __syncthreads();
  m = fmaxf(fmaxf(red[0], red[1]), fmaxf(red[2], red[3]));
  const float C = 0.18033688011112042f;  // 0.125 * log2(e)
  float e[8], s = 0.f;
#pragma unroll
  for (int j = 0; j < 4; ++j) { e[j] = exp2f((v0[j] - m) * C); s += e[j]; }
#pragma unroll
  for (int j = 0; j < 4; ++j) { e[4 + j] = exp2f((v1[j] - m) * C); s += e[4 + j]; }
#pragma unroll
  for (int o = 32; o; o >>= 1) s += __shfl_xor(s, o);
  if ((t & 63) == 0) red[4 + (t >> 6)] = s;
  __syncthreads();
  float inv = 1.f / (red[4] + red[5] + red[6] + red[7]);
  bf16x8 ov;
#pragma unroll
  for (int j = 0; j < 8; ++j) ov[j] = (short)f2bf(e[j] * inv);
  *(bf16x8*)&prow[t * 8] = ov;
}

// ======== gemm11: deep-pipelined NT GEMM: C[m][n] = sum_k A[m][k]*B[n][k] =====
// MODE 0: f32 store | 1: bf16 store | 2: bf16 scramble store (PV) | 3: f32+bias
template <int MODE, int BM>
__global__ __launch_bounds__(512, 2) void gemm11(const u16* __restrict__ A0, int lda, long sAz,
                                                 const u16* __restrict__ B0, int ldb, long sBz,
                                                 void* __restrict__ C0, int ldc, long sCz,
                                                 const float* __restrict__ bias, int K) {
  constexpr int MR = BM / 32;  // m-frags per wave (8 or 4)
  extern __shared__ __align__(16) u16 smem[];
  u16* Ab = smem;                  // [2dbuf][2kh][BM][32]
  u16* Bb = smem + 4 * BM * 32;    // [2dbuf][2kh][256][32]
  const int t = threadIdx.x, lane = t & 63, wv = t >> 6;
  const int wr = wv >> 2, wc = wv & 3;
  const int fr = lane & 15, hi = lane >> 4;

  // bijective XCD-chunk swizzle over the full grid (all our grids are %8==0)
  const int gx = gridDim.x, gy = gridDim.y;
  long L = ((long)blockIdx.z * gy + blockIdx.y) * gx + blockIdx.x;
  const long NB = (long)gx * gy * gridDim.z;
  if ((NB & 7) == 0) L = (L & 7) * (NB >> 3) + (L >> 3);
  const int bx = (int)(L % gx);
  const int by = (int)((L / gx) % gy);
  const int bz = (int)(L / ((long)gx * gy));

  const long row0 = (long)by * BM, col0 = (long)bx * 256;
  const u16* A = A0 + (long)bz * sAz;
  const u16* B = B0 + (long)bz * sBz;

  f32x4 acc[MR][4];
#pragma unroll
  for (int m = 0; m < MR; ++m)
#pragma unroll
    for (int n = 0; n < 4; ++n) acc[m][n] = (f32x4){0.f, 0.f, 0.f, 0.f};

  // stage one K-half unit of A ([BM][32]) or B ([256][32]) into dbuf d
  auto stA = [&](int d, int kh, int k0) {
#pragma unroll
    for (int i = 0; i < BM / 128; ++i) {
      const int l = i * 512 + t;
      const int r = l >> 2, sl = l & 3;
      gload_lds16(A + (row0 + r) * (long)lda + k0 + kh * 32 + sl * 8,
                  Ab + (d * 2 + kh) * BM * 32 + (i * 512 + wv * 64) * 8);
    }
  };
  auto stB = [&](int d, int kh, int k0) {
#pragma unroll
    for (int i = 0; i < 2; ++i) {
      const int l = i * 512 + t;
      const int r = l >> 2, sl = l & 3;
      gload_lds16(B + (col0 + r) * (long)ldb + k0 + kh * 32 + sl * 8,
                  Bb + (d * 2 + kh) * 256 * 32 + (i * 512 + wv * 64) * 8);
    }
  };
  auto rdA = [&](bf16x8* a, int d, int kh, int mh) {
#pragma unroll
    for (int m = 0; m < 4; ++m)
      a[m] = *(const bf16x8*)(Ab + ((d * 2 + kh) * BM + wr * (BM / 2) + mh * 64 + m * 16 + fr) * 32 + hi * 8);
  };
  auto rdB = [&](bf16x8* b, int d, int kh) {
#pragma unroll
    for (int n = 0; n < 4; ++n)
      b[n] = *(const bf16x8*)(Bb + ((d * 2 + kh) * 256 + wc * 64 + n * 16 + fr) * 32 + hi * 8);
  };
  auto mm16 = [&](bf16x8* a, bf16x8* b, int mb) {
    __builtin_amdgcn_s_setprio(1);
#pragma unroll
    for (int m = 0; m < 4; ++m)
#pragma unroll
      for (int n = 0; n < 4; ++n)
        acc[mb + m][n] = __builtin_amdgcn_mfma_f32_16x16x32_bf16(a[m], b[n], acc[mb + m][n], 0, 0, 0);
    __builtin_amdgcn_s_setprio(0);
  };

  // prologue: stage tile 0 in unit order [Bk0, Ak0, Bk1, Ak1]
  stB(0, 0, 0); stA(0, 0, 0); stB(0, 1, 0); stA(0, 1, 0);
  if constexpr (BM == 256) asm volatile("s_waitcnt vmcnt(4)" ::: "memory");
  else                     asm volatile("s_waitcnt vmcnt(3)" ::: "memory");
  __builtin_amdgcn_sched_barrier(0);
  __builtin_amdgcn_s_barrier();

  const int NT = K >> 6;
  for (int kt = 0; kt < NT; ++kt) {
    const int d = kt & 1, od = d ^ 1;
    const int kn = (kt + 1 == NT) ? 0 : ((kt + 1) << 6);  // wrap: dummy re-stage
    bf16x8 a[4], b0[4], b1[4];
    if constexpr (BM == 256) {
      // ph1: quad (m0-3, k0)
      rdA(a, d, 0, 0); rdB(b0, d, 0);
      stB(od, 0, kn);
      __builtin_amdgcn_s_barrier();
      asm volatile("s_waitcnt lgkmcnt(0)" ::: "memory");
      __builtin_amdgcn_sched_barrier(0);
      mm16(a, b0, 0);
      __builtin_amdgcn_s_barrier();
      // ph2: quad (m4-7, k0)
      rdA(a, d, 0, 1);
      stA(od, 0, kn);
      __builtin_amdgcn_s_barrier();
      asm volatile("s_waitcnt lgkmcnt(0)" ::: "memory");
      __builtin_amdgcn_sched_barrier(0);
      mm16(a, b0, 4);
      asm volatile("s_waitcnt vmcnt(4)" ::: "memory");   // publish Bk1/Ak1(kt)
      __builtin_amdgcn_sched_barrier(0);
      __builtin_amdgcn_s_barrier();
      // ph3: quad (m0-3, k1)
      rdA(a, d, 1, 0); rdB(b1, d, 1);
      stB(od, 1, kn);
      __builtin_amdgcn_s_barrier();
      asm volatile("s_waitcnt lgkmcnt(0)" ::: "memory");
      __builtin_amdgcn_sched_barrier(0);
      mm16(a, b1, 0);
      __builtin_amdgcn_s_barrier();
      // ph4: quad (m4-7, k1)
      rdA(a, d, 1, 1);
      stA(od, 1, kn);
      __builtin_amdgcn_s_barrier();
      asm volatile("s_waitcnt lgkmcnt(0)" ::: "memory");
      __builtin_amdgcn_sched_barrier(0);
      mm16(a, b1, 4);
      asm volatile("s_waitcnt vmcnt(4)" ::: "memory");   // publish Bk0/Ak0(kt+1)
      __builtin_amdgcn_sched_barrier(0);
      __builtin_amdgcn_s_barrier();
    } else {
      // ph1: k0
      rdA(a, d, 0, 0); rdB(b0, d, 0);
      stB(od, 0, kn); stA(od, 0, kn);
      __builtin_amdgcn_s_barrier();
      asm volatile("s_waitcnt lgkmcnt(0)" ::: "memory");
      __builtin_amdgcn_sched_barrier(0);
      mm16(a, b0, 0);
      asm volatile("s_waitcnt vmcnt(3)" ::: "memory");   // publish Bk1/Ak1(kt)
      __builtin_amdgcn_sched_barrier(0);
      __builtin_amdgcn_s_barrier();
      // ph2: k1
      rdA(a, d, 1, 0); rdB(b1, d, 1);
      stB(od, 1, kn); stA(od, 1, kn);
      __builtin_amdgcn_s_barrier();
      asm volatile("s_waitcnt lgkmcnt(0)" ::: "memory");
      __builtin_amdgcn_sched_barrier(0);
      mm16(a, b1, 0);
      asm volatile("s_waitcnt vmcnt(3)" ::: "memory");   // publish Bk0/Ak0(kt+1)
      __builtin_amdgcn_sched_barrier(0);
      __builtin_amdgcn_s_barrier();
    }
  }

  // epilogue
#pragma unroll
  for (int m = 0; m < MR; ++m)
#pragma unroll
    for (int n = 0; n < 4; ++n) {
      const long r0 = row0 + wr * (BM / 2) + m * 16 + hi * 4;
      const long c = col0 + wc * 64 + n * 16 + fr;
      if (MODE == 0) {
        float* C = (float*)C0 + (long)bz * sCz;
#pragma unroll
        for (int j = 0; j < 4; ++j) C[(r0 + j) * ldc + c] = acc[m][n][j];
      } else if (MODE == 1) {
        u16* C = (u16*)C0 + (long)bz * sCz;
#pragma unroll
        for (int j = 0; j < 4; ++j) C[(r0 + j) * ldc + c] = f2bf(acc[m][n][j]);
      } else if (MODE == 2) {
        // m-dim = q within batch, n-dim = h; scramble: out2[2h + (q>>10)][q&1023]
        u16* C = (u16*)C0 + (long)bz * sCz;
        const int q0 = (int)r0;
        const long dr = 2 * c + (q0 >> 10);
        bf16x4 pk;
#pragma unroll
        for (int j = 0; j < 4; ++j) pk[j] = (short)f2bf(acc[m][n][j]);
        *(bf16x4*)&C[dr * 1024 + (q0 & 1023)] = pk;
      } else {
        float* C = (float*)C0 + (long)bz * sCz;
        const float bv = bias[c];
#pragma unroll
        for (int j = 0; j < 4; ++j) C[(r0 + j) * ldc + c] = acc[m][n][j] + bv;
      }
    }
}

// ---------------- launch ----------------
extern "C" void kernel_launch(void* const* d_in, const int* in_sizes, int n_in,
                              void* d_out, int out_size, void* d_ws, size_t ws_size,
                              hipStream_t stream) {
  const float* x      = (const float*)d_in[0];  // [4,2048,1024]
  const float* w_qkv  = (const float*)d_in[1];  // [3072,1024]
  const float* w_proj = (const float*)d_in[2];  // [1024,1024]
  const float* b_proj = (const float*)d_in[3];  // [1024]
  float* out = (float*)d_out;                   // [4,2048,1024]
  char* ws = (char*)d_ws;

  // ws layout (bytes)
  u16*   xb     = (u16*)(ws + 0);          // 16 MB
  u16*   wqkvb  = (u16*)(ws + 16777216);   //  6 MB
  u16*   wprojb = (u16*)(ws + 23068672);   //  2 MB
  u16*   qkvb   = (u16*)(ws + 25165824);   // 48 MB  [8192][3072]
  u16*   vT     = (u16*)(ws + 75497472);   // 16 MB  [4][1024][2048]
  u16*   out2   = (u16*)(ws + 92274688);   // 16 MB  [8192][1024] scrambled
  float* scores = (float*)(ws + 109051904);
  const bool full = ws_size >= 209715200ull;
  u16* probs = (u16*)(ws + (full ? 176160768 : 125829120));

  const int L128 = (4 * 128 * 32 + 4 * 256 * 32) * 2;  //  96 KB
  const int L256 = (4 * 256 * 32 + 4 * 256 * 32) * 2;  // 128 KB
  hipFuncSetAttribute((const void*)gemm11<1, 128>, hipFuncAttributeMaxDynamicSharedMemorySize, L128);
  hipFuncSetAttribute((const void*)gemm11<0, 256>, hipFuncAttributeMaxDynamicSharedMemorySize, L256);
  hipFuncSetAttribute((const void*)gemm11<2, 128>, hipFuncAttributeMaxDynamicSharedMemorySize, L128);
  hipFuncSetAttribute((const void*)gemm11<3, 128>, hipFuncAttributeMaxDynamicSharedMemorySize, L128);

  // 1) f32 -> bf16
  cvt_kernel<<<4096, 256, 0, stream>>>(x, xb, 1048576);
  cvt_kernel<<<1536, 256, 0, stream>>>(w_qkv, wqkvb, 393216);
  cvt_kernel<<<512, 256, 0, stream>>>(w_proj, wprojb, 131072);

  // 2) qkv = x @ w_qkv^T  (M=8192, N=3072, K=1024) -> bf16; 768 blocks = 3 rounds
  gemm11<1, 128><<<dim3(12, 64, 1), 512, L128, stream>>>(xb, 1024, 0, wqkvb, 1024, 0,
                                                         qkvb, 3072, 0, nullptr, 1024);
  // 3) vT
  transpose_v<<<dim3(32, 16, 4), 256, 0, stream>>>(qkvb, vT);

  const long sQ = 2048L * 3072;
  if (full) {
    // 4) scores = q @ k^T (f32); 256 blocks = 1 round
    gemm11<0, 256><<<dim3(8, 8, 4), 512, L256, stream>>>(qkvb, 3072, sQ, qkvb + 1024, 3072, sQ,
                                                         scores, 2048, 2048L * 2048, nullptr, 1024);
    softmax_k<<<dim3(2048, 1, 4), 256, 0, stream>>>(scores, probs, 2048L * 2048, 2048L * 2048);
    // 5) out2 = probs @ vT^T (M=2048, N=1024, K=2048), scramble store; 256 blocks
    gemm11<2, 128><<<dim3(4, 16, 4), 512, L128, stream>>>(probs, 2048, 2048L * 2048, vT, 2048, 2048L * 1024,
                                                          out2, 1024, 2048L * 1024, nullptr, 2048);
  } else {
    for (int b = 0; b < 4; ++b) {
      const u16* qb = qkvb + (long)b * sQ;
      gemm11<0, 256><<<dim3(8, 8, 1), 512, L256, stream>>>(qb, 3072, 0, qb + 1024, 3072, 0,
                                                           scores, 2048, 0, nullptr, 1024);
      softmax_k<<<dim3(2048, 1, 1), 256, 0, stream>>>(scores, probs, 0, 0);
      gemm11<2, 128><<<dim3(4, 16, 1), 512, L128, stream>>>(probs, 2048, 0, vT + (long)b * 2048 * 1024, 2048, 0,
                                                            out2 + (long)b * 2048 * 1024, 1024, 0, nullptr, 2048);
    }
  }

  // 6) out = out2 @ w_proj^T + b_proj (M=8192, N=1024, K=1024) -> f32; 256 blocks
  gemm11<3, 128><<<dim3(4, 64, 1), 512, L128, stream>>>(out2, 1024, 0, wprojb, 1024, 0,
                                                        out, 1024, 0, b_proj, 1024);
}

// Round 7
// 303.577 us; speedup vs baseline: 3.0060x; 1.0584x over previous
//
#include <hip/hip_runtime.h>

// MultiHeadSelfAttention (faithful-bug version): qkv = x@Wqkv^T; attention over
// FULL 1024-dim "head"; scale 1/sqrt(64); probs@v; scramble reshape; proj + bias.
// B=4, S=2048, E=1024, H=1024, 3H=3072.
//
// gemm11: m201-faithful deep-pipelined NT GEMM.
//  - 512 thr / 8 waves (2M x 4N), BN=256, BM in {128,256}
//  - wave tile: BM=256 -> 128x64 (frag-read/FLOP 0.0234, the m201 ratio);
//    BM=128 -> 64x64 (0.031, read-instr-bound ~28% — used only where the
//    output geometry can't fill the chip at BM=256)
//  - LDS units [2dbuf][2kh][R][32] bf16 (64B rows, conflict-free-by-tiling)
//  - per K-tile(64): 4 phases (BM=256) or 2 phases (BM=128); vmcnt(N) before
//    barrier publishes stage completion cross-wave (counted prefetch).

typedef float f32x4 __attribute__((ext_vector_type(4)));
typedef short bf16x8 __attribute__((ext_vector_type(8)));
typedef short bf16x4 __attribute__((ext_vector_type(4)));
typedef unsigned short u16;

__device__ inline u16 f2bf(float f) {  // round-to-nearest-even f32 -> bf16 bits
  union { float f; unsigned u; } x; x.f = f;
  unsigned r = x.u + 0x7fffu + ((x.u >> 16) & 1u);
  return (u16)(r >> 16);
}

__device__ inline void gload_lds16(const void* g, void* l) {
  __builtin_amdgcn_global_load_lds(
      (const __attribute__((address_space(1))) void*)g,
      (__attribute__((address_space(3))) void*)l, 16, 0, 0);
}

// ---------------- f32 -> bf16 conversion (memory-bound) ----------------
__global__ __launch_bounds__(256) void cvt_kernel(const float* __restrict__ in,
                                                  u16* __restrict__ out, int n8) {
  int i = blockIdx.x * 256 + threadIdx.x;
  if (i >= n8) return;
  f32x4 a = *(const f32x4*)&in[(long)i * 8];
  f32x4 b = *(const f32x4*)&in[(long)i * 8 + 4];
  bf16x8 o;
#pragma unroll
  for (int j = 0; j < 4; ++j) { o[j] = (short)f2bf(a[j]); o[4 + j] = (short)f2bf(b[j]); }
  *(bf16x8*)&out[(long)i * 8] = o;
}

// ---------------- V transpose: vT[b][h][k] = qkv[b][k][2048+h] ----------------
__global__ __launch_bounds__(256) void transpose_v(const u16* __restrict__ qkvb,
                                                   u16* __restrict__ vT) {
  __shared__ u16 tile[64][72];
  const int t = threadIdx.x;
  const long b = blockIdx.z;
  const int k0 = blockIdx.x * 64, h0 = blockIdx.y * 64;
  const u16* v = qkvb + b * 2048 * 3072 + 2048;
#pragma unroll
  for (int i = 0; i < 2; ++i) {
    int s = i * 256 + t; int r = s >> 3, c = (s & 7) * 8;
    bf16x8 val = *(const bf16x8*)&v[(long)(k0 + r) * 3072 + h0 + c];
    *(bf16x8*)&tile[r][c] = val;
  }
  __syncthreads();
  u16* o = vT + b * 1024 * 2048;
#pragma unroll
  for (int i = 0; i < 2; ++i) {
    int s = i * 256 + t; int r = s >> 3, c = (s & 7) * 8;
    bf16x8 val;
#pragma unroll
    for (int j = 0; j < 8; ++j) val[j] = tile[c + j][r];
    *(bf16x8*)&o[(long)(h0 + r) * 2048 + k0 + c] = val;
  }
}

// ---------------- row softmax: probs = softmax(scores * 0.125), bf16 out ------
__global__ __launch_bounds__(256) void softmax_k(const float* __restrict__ S,
                                                 u16* __restrict__ P,
                                                 long sS, long sP) {
  const int t = threadIdx.x;
  const float* row = S + (long)blockIdx.z * sS + (long)blockIdx.x * 2048;
  u16* prow = P + (long)blockIdx.z * sP + (long)blockIdx.x * 2048;
  f32x4 v0 = *(const f32x4*)&row[t * 8];
  f32x4 v1 = *(const f32x4*)&row[t * 8 + 4];
  float m = v0[0];
#pragma unroll
  for (int j = 1; j < 4; ++j) m = fmaxf(m, v0[j]);
#pragma unroll
  for (int j = 0; j < 4; ++j) m = fmaxf(m, v1[j]);
#pragma unroll
  for (int o = 32; o; o >>= 1) m = fmaxf(m, __shfl_xor(m, o));
  __shared__ float red[8];
  if ((t & 63) == 0) red[t >> 6] = m;
  __syncthreads();
  m = fmaxf(fmaxf(red[0], red[1]), fmaxf(red[2], red[3]));
  const float C = 0.18033688011112042f;  // 0.125 * log2(e)
  float e[8], s = 0.f;
#pragma unroll
  for (int j = 0; j < 4; ++j) { e[j] = exp2f((v0[j] - m) * C); s += e[j]; }
#pragma unroll
  for (int j = 0; j < 4; ++j) { e[4 + j] = exp2f((v1[j] - m) * C); s += e[4 + j]; }
#pragma unroll
  for (int o = 32; o; o >>= 1) s += __shfl_xor(s, o);
  if ((t & 63) == 0) red[4 + (t >> 6)] = s;
  __syncthreads();
  float inv = 1.f / (red[4] + red[5] + red[6] + red[7]);
  bf16x8 ov;
#pragma unroll
  for (int j = 0; j < 8; ++j) ov[j] = (short)f2bf(e[j] * inv);
  *(bf16x8*)&prow[t * 8] = ov;
}

// ======== gemm11: deep-pipelined NT GEMM: C[m][n] = sum_k A[m][k]*B[n][k] =====
// MODE 0: f32 store | 1: bf16 store | 2: bf16 scramble store (PV) | 3: f32+bias
template <int MODE, int BM>
__global__ __launch_bounds__(512, 2) void gemm11(const u16* __restrict__ A0, int lda, long sAz,
                                                 const u16* __restrict__ B0, int ldb, long sBz,
                                                 void* __restrict__ C0, int ldc, long sCz,
                                                 const float* __restrict__ bias, int K) {
  constexpr int MR = BM / 32;  // m-frags per wave (8 or 4)
  extern __shared__ __align__(16) u16 smem[];
  u16* Ab = smem;                  // [2dbuf][2kh][BM][32]
  u16* Bb = smem + 4 * BM * 32;    // [2dbuf][2kh][256][32]
  const int t = threadIdx.x, lane = t & 63, wv = t >> 6;
  const int wr = wv >> 2, wc = wv & 3;
  const int fr = lane & 15, hi = lane >> 4;

  // bijective XCD-chunk swizzle over the full grid (all our grids are %8==0)
  const int gx = gridDim.x, gy = gridDim.y;
  long L = ((long)blockIdx.z * gy + blockIdx.y) * gx + blockIdx.x;
  const long NB = (long)gx * gy * gridDim.z;
  if ((NB & 7) == 0) L = (L & 7) * (NB >> 3) + (L >> 3);
  const int bx = (int)(L % gx);
  const int by = (int)((L / gx) % gy);
  const int bz = (int)(L / ((long)gx * gy));

  const long row0 = (long)by * BM, col0 = (long)bx * 256;
  const u16* A = A0 + (long)bz * sAz;
  const u16* B = B0 + (long)bz * sBz;

  f32x4 acc[MR][4];
#pragma unroll
  for (int m = 0; m < MR; ++m)
#pragma unroll
    for (int n = 0; n < 4; ++n) acc[m][n] = (f32x4){0.f, 0.f, 0.f, 0.f};

  // stage one K-half unit of A ([BM][32]) or B ([256][32]) into dbuf d
  auto stA = [&](int d, int kh, int k0) {
#pragma unroll
    for (int i = 0; i < BM / 128; ++i) {
      const int l = i * 512 + t;
      const int r = l >> 2, sl = l & 3;
      gload_lds16(A + (row0 + r) * (long)lda + k0 + kh * 32 + sl * 8,
                  Ab + (d * 2 + kh) * BM * 32 + (i * 512 + wv * 64) * 8);
    }
  };
  auto stB = [&](int d, int kh, int k0) {
#pragma unroll
    for (int i = 0; i < 2; ++i) {
      const int l = i * 512 + t;
      const int r = l >> 2, sl = l & 3;
      gload_lds16(B + (col0 + r) * (long)ldb + k0 + kh * 32 + sl * 8,
                  Bb + (d * 2 + kh) * 256 * 32 + (i * 512 + wv * 64) * 8);
    }
  };
  auto rdA = [&](bf16x8* a, int d, int kh, int mh) {
#pragma unroll
    for (int m = 0; m < 4; ++m)
      a[m] = *(const bf16x8*)(Ab + ((d * 2 + kh) * BM + wr * (BM / 2) + mh * 64 + m * 16 + fr) * 32 + hi * 8);
  };
  auto rdB = [&](bf16x8* b, int d, int kh) {
#pragma unroll
    for (int n = 0; n < 4; ++n)
      b[n] = *(const bf16x8*)(Bb + ((d * 2 + kh) * 256 + wc * 64 + n * 16 + fr) * 32 + hi * 8);
  };
  auto mm16 = [&](bf16x8* a, bf16x8* b, int mb) {
    __builtin_amdgcn_s_setprio(1);
#pragma unroll
    for (int m = 0; m < 4; ++m)
#pragma unroll
      for (int n = 0; n < 4; ++n)
        acc[mb + m][n] = __builtin_amdgcn_mfma_f32_16x16x32_bf16(a[m], b[n], acc[mb + m][n], 0, 0, 0);
    __builtin_amdgcn_s_setprio(0);
  };

  // prologue: stage tile 0 in unit order [Bk0, Ak0, Bk1, Ak1]
  stB(0, 0, 0); stA(0, 0, 0); stB(0, 1, 0); stA(0, 1, 0);
  if constexpr (BM == 256) asm volatile("s_waitcnt vmcnt(4)" ::: "memory");
  else                     asm volatile("s_waitcnt vmcnt(3)" ::: "memory");
  __builtin_amdgcn_sched_barrier(0);
  __builtin_amdgcn_s_barrier();

  const int NT = K >> 6;
  for (int kt = 0; kt < NT; ++kt) {
    const int d = kt & 1, od = d ^ 1;
    const int kn = (kt + 1 == NT) ? 0 : ((kt + 1) << 6);  // wrap: dummy re-stage
    bf16x8 a[4], b0[4], b1[4];
    if constexpr (BM == 256) {
      // ph1: quad (m0-3, k0)
      rdA(a, d, 0, 0); rdB(b0, d, 0);
      stB(od, 0, kn);
      __builtin_amdgcn_s_barrier();
      asm volatile("s_waitcnt lgkmcnt(0)" ::: "memory");
      __builtin_amdgcn_sched_barrier(0);
      mm16(a, b0, 0);
      __builtin_amdgcn_s_barrier();
      // ph2: quad (m4-7, k0)
      rdA(a, d, 0, 1);
      stA(od, 0, kn);
      __builtin_amdgcn_s_barrier();
      asm volatile("s_waitcnt lgkmcnt(0)" ::: "memory");
      __builtin_amdgcn_sched_barrier(0);
      mm16(a, b0, 4);
      asm volatile("s_waitcnt vmcnt(4)" ::: "memory");   // publish Bk1/Ak1(kt)
      __builtin_amdgcn_sched_barrier(0);
      __builtin_amdgcn_s_barrier();
      // ph3: quad (m0-3, k1)
      rdA(a, d, 1, 0); rdB(b1, d, 1);
      stB(od, 1, kn);
      __builtin_amdgcn_s_barrier();
      asm volatile("s_waitcnt lgkmcnt(0)" ::: "memory");
      __builtin_amdgcn_sched_barrier(0);
      mm16(a, b1, 0);
      __builtin_amdgcn_s_barrier();
      // ph4: quad (m4-7, k1)
      rdA(a, d, 1, 1);
      stA(od, 1, kn);
      __builtin_amdgcn_s_barrier();
      asm volatile("s_waitcnt lgkmcnt(0)" ::: "memory");
      __builtin_amdgcn_sched_barrier(0);
      mm16(a, b1, 4);
      asm volatile("s_waitcnt vmcnt(4)" ::: "memory");   // publish Bk0/Ak0(kt+1)
      __builtin_amdgcn_sched_barrier(0);
      __builtin_amdgcn_s_barrier();
    } else {
      // ph1: k0
      rdA(a, d, 0, 0); rdB(b0, d, 0);
      stB(od, 0, kn); stA(od, 0, kn);
      __builtin_amdgcn_s_barrier();
      asm volatile("s_waitcnt lgkmcnt(0)" ::: "memory");
      __builtin_amdgcn_sched_barrier(0);
      mm16(a, b0, 0);
      asm volatile("s_waitcnt vmcnt(3)" ::: "memory");   // publish Bk1/Ak1(kt)
      __builtin_amdgcn_sched_barrier(0);
      __builtin_amdgcn_s_barrier();
      // ph2: k1
      rdA(a, d, 1, 0); rdB(b1, d, 1);
      stB(od, 1, kn); stA(od, 1, kn);
      __builtin_amdgcn_s_barrier();
      asm volatile("s_waitcnt lgkmcnt(0)" ::: "memory");
      __builtin_amdgcn_sched_barrier(0);
      mm16(a, b1, 0);
      asm volatile("s_waitcnt vmcnt(3)" ::: "memory");   // publish Bk0/Ak0(kt+1)
      __builtin_amdgcn_sched_barrier(0);
      __builtin_amdgcn_s_barrier();
    }
  }

  // epilogue
#pragma unroll
  for (int m = 0; m < MR; ++m)
#pragma unroll
    for (int n = 0; n < 4; ++n) {
      const long r0 = row0 + wr * (BM / 2) + m * 16 + hi * 4;
      const long c = col0 + wc * 64 + n * 16 + fr;
      if (MODE == 0) {
        float* C = (float*)C0 + (long)bz * sCz;
#pragma unroll
        for (int j = 0; j < 4; ++j) C[(r0 + j) * ldc + c] = acc[m][n][j];
      } else if (MODE == 1) {
        u16* C = (u16*)C0 + (long)bz * sCz;
#pragma unroll
        for (int j = 0; j < 4; ++j) C[(r0 + j) * ldc + c] = f2bf(acc[m][n][j]);
      } else if (MODE == 2) {
        // m-dim = q within batch, n-dim = h; scramble: out2[2h + (q>>10)][q&1023]
        u16* C = (u16*)C0 + (long)bz * sCz;
        const int q0 = (int)r0;
        const long dr = 2 * c + (q0 >> 10);
        bf16x4 pk;
#pragma unroll
        for (int j = 0; j < 4; ++j) pk[j] = (short)f2bf(acc[m][n][j]);
        *(bf16x4*)&C[dr * 1024 + (q0 & 1023)] = pk;
      } else {
        float* C = (float*)C0 + (long)bz * sCz;
        const float bv = bias[c];
#pragma unroll
        for (int j = 0; j < 4; ++j) C[(r0 + j) * ldc + c] = acc[m][n][j] + bv;
      }
    }
}

// ---------------- launch ----------------
extern "C" void kernel_launch(void* const* d_in, const int* in_sizes, int n_in,
                              void* d_out, int out_size, void* d_ws, size_t ws_size,
                              hipStream_t stream) {
  const float* x      = (const float*)d_in[0];  // [4,2048,1024]
  const float* w_qkv  = (const float*)d_in[1];  // [3072,1024]
  const float* w_proj = (const float*)d_in[2];  // [1024,1024]
  const float* b_proj = (const float*)d_in[3];  // [1024]
  float* out = (float*)d_out;                   // [4,2048,1024]
  char* ws = (char*)d_ws;

  // ws layout (bytes)
  u16*   xb     = (u16*)(ws + 0);          // 16 MB
  u16*   wqkvb  = (u16*)(ws + 16777216);   //  6 MB
  u16*   wprojb = (u16*)(ws + 23068672);   //  2 MB
  u16*   qkvb   = (u16*)(ws + 25165824);   // 48 MB  [8192][3072]
  u16*   vT     = (u16*)(ws + 75497472);   // 16 MB  [4][1024][2048]
  u16*   out2   = (u16*)(ws + 92274688);   // 16 MB  [8192][1024] scrambled
  float* scores = (float*)(ws + 109051904);
  const bool full = ws_size >= 209715200ull;
  u16* probs = (u16*)(ws + (full ? 176160768 : 125829120));

  const int L128 = (4 * 128 * 32 + 4 * 256 * 32) * 2;  //  96 KB
  const int L256 = (4 * 256 * 32 + 4 * 256 * 32) * 2;  // 128 KB
  hipFuncSetAttribute((const void*)gemm11<1, 256>, hipFuncAttributeMaxDynamicSharedMemorySize, L256);
  hipFuncSetAttribute((const void*)gemm11<0, 256>, hipFuncAttributeMaxDynamicSharedMemorySize, L256);
  hipFuncSetAttribute((const void*)gemm11<2, 128>, hipFuncAttributeMaxDynamicSharedMemorySize, L128);
  hipFuncSetAttribute((const void*)gemm11<3, 128>, hipFuncAttributeMaxDynamicSharedMemorySize, L128);

  // 1) f32 -> bf16
  cvt_kernel<<<4096, 256, 0, stream>>>(x, xb, 1048576);
  cvt_kernel<<<1536, 256, 0, stream>>>(w_qkv, wqkvb, 393216);
  cvt_kernel<<<512, 256, 0, stream>>>(w_proj, wprojb, 131072);

  // 2) qkv = x @ w_qkv^T  (M=8192, N=3072, K=1024) -> bf16; 384 blocks, 128x64 wave tile
  gemm11<1, 256><<<dim3(12, 32, 1), 512, L256, stream>>>(xb, 1024, 0, wqkvb, 1024, 0,
                                                         qkvb, 3072, 0, nullptr, 1024);
  // 3) vT
  transpose_v<<<dim3(32, 16, 4), 256, 0, stream>>>(qkvb, vT);

  const long sQ = 2048L * 3072;
  if (full) {
    // 4) scores = q @ k^T (f32); 256 blocks = 1 round
    gemm11<0, 256><<<dim3(8, 8, 4), 512, L256, stream>>>(qkvb, 3072, sQ, qkvb + 1024, 3072, sQ,
                                                         scores, 2048, 2048L * 2048, nullptr, 1024);
    softmax_k<<<dim3(2048, 1, 4), 256, 0, stream>>>(scores, probs, 2048L * 2048, 2048L * 2048);
    // 5) out2 = probs @ vT^T (M=2048, N=1024, K=2048), scramble store; 256 blocks
    gemm11<2, 128><<<dim3(4, 16, 4), 512, L128, stream>>>(probs, 2048, 2048L * 2048, vT, 2048, 2048L * 1024,
                                                          out2, 1024, 2048L * 1024, nullptr, 2048);
  } else {
    for (int b = 0; b < 4; ++b) {
      const u16* qb = qkvb + (long)b * sQ;
      gemm11<0, 256><<<dim3(8, 8, 1), 512, L256, stream>>>(qb, 3072, 0, qb + 1024, 3072, 0,
                                                           scores, 2048, 0, nullptr, 1024);
      softmax_k<<<dim3(2048, 1, 1), 256, 0, stream>>>(scores, probs, 0, 0);
      gemm11<2, 128><<<dim3(4, 16, 1), 512, L128, stream>>>(probs, 2048, 0, vT + (long)b * 2048 * 1024, 2048, 0,
                                                            out2 + (long)b * 2048 * 1024, 1024, 0, nullptr, 2048);
    }
  }

  // 6) out = out2 @ w_proj^T + b_proj (M=8192, N=1024, K=1024) -> f32; 256 blocks
  gemm11<3, 128><<<dim3(4, 64, 1), 512, L128, stream>>>(out2, 1024, 0, wprojb, 1024, 0,
                                                        out, 1024, 0, b_proj, 1024);
}